// Round 9
// baseline (2367.356 us; speedup 1.0000x reference)
//
#include <hip/hip_runtime.h>
#include <hip/hip_bf16.h>

#define BN_EPS 1e-4f

typedef __attribute__((ext_vector_type(8))) short short8;   // 8 bf16 = 4 VGPR (MFMA A/B frag)
typedef __attribute__((ext_vector_type(4))) float float4e;  // MFMA C/D frag

__device__ __forceinline__ int rfl(int x) { return __builtin_amdgcn_readfirstlane(x); }

__device__ __forceinline__ float ldf(const __hip_bfloat16* p) { return __bfloat162float(*p); }
__device__ __forceinline__ void stf(__hip_bfloat16* p, float v) { *p = __float2bfloat16(v); }

__device__ __forceinline__ short bfbits(float x) {
    __hip_bfloat16 h = __float2bfloat16(x);
    short s;
    __builtin_memcpy(&s, &h, 2);
    return s;
}
__device__ __forceinline__ short8 cvt8(float4 a, float4 b) {
    short8 r;
    r[0] = bfbits(a.x); r[1] = bfbits(a.y); r[2] = bfbits(a.z); r[3] = bfbits(a.w);
    r[4] = bfbits(b.x); r[5] = bfbits(b.y); r[6] = bfbits(b.z); r[7] = bfbits(b.w);
    return r;
}

// ---- pack W fp32 [27][CIN][COUT] -> bf16 B-fragment table [27][KT][NT][lane][8] ----
// element j of lane = W[t][kt*32 + (lane>>4)*8 + j][nt*16 + (lane&15)]
__global__ __launch_bounds__(256) void k_pack(const float* __restrict__ src,
                                              __hip_bfloat16* __restrict__ dst,
                                              int CIN, int COUT, int KT, int NT, int total) {
    int i = blockIdx.x * 256 + threadIdx.x;
    if (i >= total) return;
    int j = i & 7, lane = (i >> 3) & 63;
    int g = i >> 9;
    int nt = g % NT; g /= NT;
    int kt = g % KT; g /= KT;
    int t = g;
    int q = lane >> 4, c = lane & 15;
    dst[i] = __float2bfloat16(src[((size_t)t * CIN + kt * 32 + q * 8 + j) * COUT + nt * 16 + c]);
}

// ---------------- xv = subconv(feats[N,3], nbr_fine, W_sub) -> bf16 ----------------
__global__ __launch_bounds__(256) void k_xv(const float* __restrict__ feats,
                                            const int* __restrict__ nbr,
                                            const float* __restrict__ W,
                                            __hip_bfloat16* __restrict__ out, int N) {
    int n = blockIdx.x * 256 + threadIdx.x;
    if (n >= N) return;
    float acc[32];
#pragma unroll
    for (int d = 0; d < 32; ++d) acc[d] = 0.f;
    const int* nb = nbr + (size_t)n * 27;
    for (int k = 0; k < 27; ++k) {
        int idx = nb[k];
        if (idx < 0) continue;
        float f0 = feats[(size_t)idx * 3 + 0];
        float f1 = feats[(size_t)idx * 3 + 1];
        float f2 = feats[(size_t)idx * 3 + 2];
        const float* w = W + k * 96;  // k uniform -> scalar loads
#pragma unroll
        for (int d = 0; d < 32; ++d)
            acc[d] += f0 * w[d] + f1 * w[32 + d] + f2 * w[64 + d];
    }
    short8* o = (short8*)(out + (size_t)n * 32);
#pragma unroll
    for (int c = 0; c < 4; ++c) {
        short8 r;
#pragma unroll
        for (int j = 0; j < 8; ++j) r[j] = bfbits(acc[c * 8 + j]);
        o[c] = r;
    }
}

// ---------------- MFMA submanifold conv, D-deep gather pipeline ----------------
// Wave per 16-row tile. A-frags gathered directly from global (per-lane 16B
// contiguous, no LDS transpose). Row idx from LDS tap-major table (padded to
// 27+D taps). D-slot register ring: slot s=k%D's gather issues D taps before
// its MFMA consume -> load->use distance ~ D taps of compute (R8 diagnosis:
// 1-deep prefetch left ~400 cyc/tap exposed). k-loop fully unrolled so slot
// indices are compile-time. Invalid rows -> zero frags (branchless); tap skip
// scalar. MODE 0: bf16 single src | 1: fp32 src + in-reg cvt | 2: bf16 dual.
template <int CIN, int COUT, int MODE, int D>
__global__ __launch_bounds__(256, 4) void k_conv(const void* __restrict__ inAv,
                                                 const void* __restrict__ inBv,
                                                 const int* __restrict__ nbr,
                                                 const __hip_bfloat16* __restrict__ Wp,
                                                 __hip_bfloat16* __restrict__ out,
                                                 int nrows,
                                                 float* __restrict__ ssum,
                                                 float* __restrict__ ssq) {
    constexpr int KT = CIN / 32;   // MFMA k-tiles
    constexpr int NT = COUT / 16;  // MFMA n-tiles
    constexpr int TT = 27 + D;     // taps incl. pipeline pad
    __shared__ int sidx[4][16 * (27 + 6)];  // sized for Dmax=6
    const __hip_bfloat16* inAb = (const __hip_bfloat16*)inAv;
    const __hip_bfloat16* inBb = (const __hip_bfloat16*)inBv;
    const float* inAf = (const float*)inAv;
    const int tid = threadIdx.x;
    const int lane = tid & 63;
    const int wv = tid >> 6;
    const int m15 = lane & 15;
    const int q = lane >> 4;
    int* my = sidx[wv];
    int wid = blockIdx.x * 4 + wv;
    int nw = gridDim.x * 4;
    const int ntile = (nrows + 15) / 16;
    float sS[NT], sQ[NT];
#pragma unroll
    for (int nt = 0; nt < NT; ++nt) { sS[nt] = 0.f; sQ[nt] = 0.f; }

    for (int tile = wid; tile < ntile; tile += nw) {
        const int row0 = rfl(tile) * 16;
        int nr = nrows - row0;
        nr = nr > 16 ? 16 : nr;
        // ---- stage idx table (coalesced read, tap-major scatter, -1 pad) ----
        for (int t = lane; t < 16 * TT; t += 64) my[t] = -1;
        const int* src = nbr + (size_t)row0 * 27;
        const int tot = nr * 27;
        for (int t = lane; t < tot; t += 64) {
            int r = t / 27;
            my[(t - r * 27) * 16 + r] = src[t];
        }
        float4e acc[NT];
#pragma unroll
        for (int nt = 0; nt < NT; ++nt) acc[nt] = (float4e)0.f;

        short8 gs[D][KT];
        float4 gf[D][4];
        int irs[D], ms[D];
        auto load_g = [&](int ir, short8 g[KT], float4 f[4]) {
            size_t id = (size_t)(ir < 0 ? 0 : ir);
            if (MODE == 0) {
                g[0] = *(const short8*)(inAb + id * 32 + q * 8);
            } else if (MODE == 2) {
                g[0] = *(const short8*)(inAb + id * 32 + q * 8);
                g[1] = *(const short8*)(inBb + id * 32 + q * 8);
            } else {
                const float* b = inAf + id * 64 + q * 8;
                f[0] = *(const float4*)(b);
                f[1] = *(const float4*)(b + 4);
                f[2] = *(const float4*)(b + 32);
                f[3] = *(const float4*)(b + 36);
            }
        };
        // ---- fill the D-slot ring ----
#pragma unroll
        for (int d = 0; d < D; ++d) {
            irs[d] = my[d * 16 + m15];
            ms[d] = rfl((int)(__ballot(irs[d] >= 0) & 0xffff));
            if (ms[d]) load_g(irs[d], gs[d], gf[d]);
        }
        // ---- main tap loop (fully unrolled; slot index compile-time) ----
#pragma unroll
        for (int k = 0; k < 27; ++k) {
            const int s = k % D;
            if (ms[s]) {
                short8 a[KT];
                if (MODE == 1) {
                    a[0] = cvt8(gf[s][0], gf[s][1]);
                    a[1] = cvt8(gf[s][2], gf[s][3]);
                } else {
#pragma unroll
                    for (int kt = 0; kt < KT; ++kt) a[kt] = gs[s][kt];
                }
                short8 z = (short8)(short)0;
#pragma unroll
                for (int kt = 0; kt < KT; ++kt) a[kt] = (irs[s] >= 0) ? a[kt] : z;
                const short8* bp = (const short8*)Wp + (size_t)k * KT * NT * 64 + lane;
#pragma unroll
                for (int nt = 0; nt < NT; ++nt) {
#pragma unroll
                    for (int kt = 0; kt < KT; ++kt) {
                        short8 b = bp[(kt * NT + nt) * 64];
                        acc[nt] = __builtin_amdgcn_mfma_f32_16x16x32_bf16(a[kt], b, acc[nt], 0, 0, 0);
                    }
                }
            }
            // refill slot s with tap k+D (pad taps are -1 -> skipped)
            int ir = my[(k + D) * 16 + m15];
            irs[s] = ir;
            ms[s] = rfl((int)(__ballot(ir >= 0) & 0xffff));
            if (ms[s]) load_g(ir, gs[s], gf[s]);
        }
        // ---- store C (col=lane&15, row=quad*4+reg) + BN stats ----
#pragma unroll
        for (int nt = 0; nt < NT; ++nt) {
#pragma unroll
            for (int r = 0; r < 4; ++r) {
                int rowg = row0 + q * 4 + r;
                if (rowg < nrows) {
                    float v = acc[nt][r];
                    stf(out + (size_t)rowg * COUT + nt * 16 + m15, v);
                    sS[nt] += v;
                    sQ[nt] += v * v;
                }
            }
        }
    }
    // ---- stats: reduce over quads (same col), one atomic per (col,nt) ----
#pragma unroll
    for (int nt = 0; nt < NT; ++nt) {
        float v = sS[nt], w = sQ[nt];
        v += __shfl_xor(v, 16); v += __shfl_xor(v, 32);
        w += __shfl_xor(w, 16); w += __shfl_xor(w, 32);
        if (lane < 16) {
            atomicAdd(&ssum[nt * 16 + lane], v);
            atomicAdd(&ssq[nt * 16 + lane], w);
        }
    }
}

// ---------------- BN finalize: scale/shift from sums ----------------
__global__ void k_fin(const float* __restrict__ ssum, const float* __restrict__ ssq,
                      const float* __restrict__ g, const float* __restrict__ b,
                      float* __restrict__ scale, float* __restrict__ shift,
                      int C, float invN) {
    int c = blockIdx.x * blockDim.x + threadIdx.x;
    if (c >= C) return;
    float mu = ssum[c] * invN;
    float var = fmaxf(ssq[c] * invN - mu * mu, 0.f);
    float s = g[c] * rsqrtf(var + BN_EPS);
    scale[c] = s;
    shift[c] = b[c] - mu * s;
}

// ---- e0 = bnrelu(e0raw) in place (bf16); down[parent] += e0 @ W_down[off] (fp32 atomics) ----
__global__ __launch_bounds__(256) void k_down(__hip_bfloat16* __restrict__ e0,
                                              const int* __restrict__ parent,
                                              const int* __restrict__ child,
                                              const float* __restrict__ Wd,
                                              const float* __restrict__ sc,
                                              const float* __restrict__ sh,
                                              float* __restrict__ down, int N) {
    const int lane = threadIdx.x & 63;
    int wid = blockIdx.x * 4 + (threadIdx.x >> 6);
    int nw = gridDim.x * 4;
    for (int row = wid; row < N; row += nw) {
        int urow = rfl(row);
        float v = 0.f;
        if (lane < 32) {
            float r = ldf(e0 + (size_t)urow * 32 + lane);
            v = fmaxf(fmaf(r, sc[lane], sh[lane]), 0.f);
            stf(e0 + (size_t)urow * 32 + lane, v);  // post-BN e0, consumed by dec
        }
        int par = rfl(parent[urow]);
        int off = rfl(child[urow]);
        float acc = 0.f;
        const float* wb = Wd + (size_t)off * 2048 + lane;  // W_down[off][c][lane]
#pragma unroll
        for (int c = 0; c < 32; ++c)
            acc = fmaf(__shfl(v, c), wb[c * 64], acc);
        atomicAdd(&down[(size_t)par * 64 + lane], acc);
    }
}

// ---- up[n] = bnrelu(e1raw)[parent[n]] @ W_up[off[n]] -> bf16 ----
__global__ __launch_bounds__(256) void k_up(const __hip_bfloat16* __restrict__ e1raw,
                                            const int* __restrict__ parent,
                                            const int* __restrict__ child,
                                            const float* __restrict__ Wu,
                                            const float* __restrict__ sc,
                                            const float* __restrict__ sh,
                                            __hip_bfloat16* __restrict__ up, int N) {
    const int lane = threadIdx.x & 63;
    int wid = blockIdx.x * 4 + (threadIdx.x >> 6);
    int nw = gridDim.x * 4;
    for (int row = wid; row < N; row += nw) {
        int urow = rfl(row);
        int par = rfl(parent[urow]);
        int off = rfl(child[urow]);
        float e = ldf(e1raw + (size_t)par * 64 + lane);
        float v = fmaxf(fmaf(e, sc[lane], sh[lane]), 0.f);  // BN on the fly
        int d = lane & 31, hi = lane >> 5;
        float acc = 0.f;
        const float* wb = Wu + (size_t)off * 2048 + (size_t)hi * 1024 + d;
#pragma unroll
        for (int c = 0; c < 32; ++c)
            acc = fmaf(__shfl(v, hi * 32 + c), wb[c * 32], acc);
        acc += __shfl_xor(acc, 32);
        if (hi == 0) stf(up + (size_t)urow * 32 + d, acc);
    }
}

// ---- feature = bnrelu(decraw); y = feature @ W_lin + b_lin ----
__global__ __launch_bounds__(256) void k_out(const __hip_bfloat16* __restrict__ dec,
                                             const float* __restrict__ sc,
                                             const float* __restrict__ sh,
                                             const float* __restrict__ Wl,
                                             const float* __restrict__ bl,
                                             float* __restrict__ y,
                                             float* __restrict__ feat, int N) {
    int n = blockIdx.x * 256 + threadIdx.x;
    if (n >= N) return;
    float f[32];
    const __hip_bfloat162* p = (const __hip_bfloat162*)(dec + (size_t)n * 32);
#pragma unroll
    for (int j = 0; j < 16; ++j) {
        float2 t = __bfloat1622float2(p[j]);
        f[2 * j + 0] = fmaxf(fmaf(t.x, sc[2 * j + 0], sh[2 * j + 0]), 0.f);
        f[2 * j + 1] = fmaxf(fmaf(t.y, sc[2 * j + 1], sh[2 * j + 1]), 0.f);
    }
    float4* fo = (float4*)(feat + (size_t)n * 32);
#pragma unroll
    for (int j = 0; j < 8; ++j)
        fo[j] = make_float4(f[4 * j], f[4 * j + 1], f[4 * j + 2], f[4 * j + 3]);
    float acc[20];
#pragma unroll
    for (int qq = 0; qq < 20; ++qq) acc[qq] = bl[qq];
#pragma unroll
    for (int c = 0; c < 32; ++c) {
        float fc = f[c];
#pragma unroll
        for (int qq = 0; qq < 20; ++qq) acc[qq] = fmaf(fc, Wl[c * 20 + qq], acc[qq]);
    }
    float4* yo = (float4*)(y + (size_t)n * 20);
#pragma unroll
    for (int j = 0; j < 5; ++j)
        yo[j] = make_float4(acc[4 * j], acc[4 * j + 1], acc[4 * j + 2], acc[4 * j + 3]);
}

extern "C" void kernel_launch(void* const* d_in, const int* in_sizes, int n_in,
                              void* d_out, int out_size, void* d_ws, size_t ws_size,
                              hipStream_t stream) {
    const float* feats = (const float*)d_in[0];
    const int* nbr_f   = (const int*)d_in[1];
    const int* nbr_c   = (const int*)d_in[2];
    const int* parent  = (const int*)d_in[3];
    const int* child   = (const int*)d_in[4];
    const float* W_sub = (const float*)d_in[5];
    const float* W_e0  = (const float*)d_in[6];
    const float* g0    = (const float*)d_in[7];
    const float* b0    = (const float*)d_in[8];
    const float* W_dn  = (const float*)d_in[9];
    const float* W_e1  = (const float*)d_in[10];
    const float* g1    = (const float*)d_in[11];
    const float* b1    = (const float*)d_in[12];
    const float* W_up  = (const float*)d_in[13];
    const float* W_dec = (const float*)d_in[14];
    const float* g_o   = (const float*)d_in[15];
    const float* b_o   = (const float*)d_in[16];
    const float* W_lin = (const float*)d_in[17];
    const float* b_lin = (const float*)d_in[18];

    const int N = in_sizes[0] / 3;
    const int M = in_sizes[2] / 27;

    // --- workspace: xvb bf16 [0..N*16 fl) / down fp32 [0..M*64 fl) /
    //     up bf16 [0..N*16 fl) + decraw bf16 [N*16..N*32 fl); stats at R ---
    float* wsf = (float*)d_ws;
    size_t R = (size_t)M * 64;
    if ((size_t)N * 32 > R) R = (size_t)N * 32;
    __hip_bfloat16* xvb = (__hip_bfloat16*)wsf;
    float* down = wsf;
    __hip_bfloat16* up     = (__hip_bfloat16*)wsf;
    __hip_bfloat16* decraw = (__hip_bfloat16*)(wsf + (size_t)N * 16);
    float* stats = wsf + R;
    // stats map: 0 sum0[32] | 32 sq0[32] | 64 sum1[64] | 128 sq1[64] |
    //            192 sumo[32] | 224 sqo[32] | 256 scale0 | 288 shift0 |
    //            320 scale1[64] | 384 shift1[64] | 448 scaleo | 480 shifto

    // --- d_out scratch: e0 bf16 [0..N*16 fl), e1raw bf16 [N*16..N*16+M*32 fl),
    // packed weights after; all dead before k_out writes y/feat ---
    __hip_bfloat16* e0    = (__hip_bfloat16*)d_out;
    __hip_bfloat16* e1raw = (__hip_bfloat16*)((float*)d_out + (size_t)N * 16);
    __hip_bfloat16* Wp0   = (__hip_bfloat16*)((float*)d_out + (size_t)N * 16 + (size_t)M * 32);
    const int T0 = 27 * 1 * 2 * 512;  // e0 pack: KT1 NT2
    const int T1 = 27 * 2 * 4 * 512;  // e1 pack: KT2 NT4
    const int T2 = 27 * 2 * 2 * 512;  // dec pack: KT2 NT2
    __hip_bfloat16* Wp1 = Wp0 + T0;
    __hip_bfloat16* Wp2 = Wp1 + T1;
    float* y    = (float*)d_out;
    float* feat = y + (size_t)N * 20;

    const int nblk = (N + 255) / 256;
    const int G = 2048;

    hipMemsetAsync(stats, 0, 256 * sizeof(float), stream);
    k_pack<<<(T0 + 255) / 256, 256, 0, stream>>>(W_e0, Wp0, 32, 32, 1, 2, T0);
    k_pack<<<(T1 + 255) / 256, 256, 0, stream>>>(W_e1, Wp1, 64, 64, 2, 4, T1);
    k_pack<<<(T2 + 255) / 256, 256, 0, stream>>>(W_dec, Wp2, 64, 32, 2, 2, T2);

    k_xv<<<nblk, 256, 0, stream>>>(feats, nbr_f, W_sub, xvb, N);
    k_conv<32, 32, 0, 6><<<G, 256, 0, stream>>>(xvb, nullptr, nbr_f, Wp0, e0, N,
                                                stats + 0, stats + 32);
    // xvb dead; zero `down` (same region) for the atomic segment-sum
    hipMemsetAsync(down, 0, (size_t)M * 64 * sizeof(float), stream);
    k_fin<<<1, 64, 0, stream>>>(stats + 0, stats + 32, g0, b0,
                                stats + 256, stats + 288, 32, 1.f / (float)N);
    k_down<<<G, 256, 0, stream>>>(e0, parent, child, W_dn,
                                  stats + 256, stats + 288, down, N);
    k_conv<64, 64, 1, 3><<<G, 256, 0, stream>>>(down, nullptr, nbr_c, Wp1, e1raw, M,
                                                stats + 64, stats + 128);
    k_fin<<<1, 64, 0, stream>>>(stats + 64, stats + 128, g1, b1,
                                stats + 320, stats + 384, 64, 1.f / (float)M);
    k_up<<<G, 256, 0, stream>>>(e1raw, parent, child, W_up,
                                stats + 320, stats + 384, up, N);
    k_conv<64, 32, 2, 4><<<G, 256, 0, stream>>>(e0, up, nbr_f, Wp2, decraw, N,
                                                stats + 192, stats + 224);
    k_fin<<<1, 64, 0, stream>>>(stats + 192, stats + 224, g_o, b_o,
                                stats + 448, stats + 480, 32, 1.f / (float)N);
    k_out<<<nblk, 256, 0, stream>>>(decraw, stats + 448, stats + 480, W_lin, b_lin,
                                    y, feat, N);
}